// Round 11
// baseline (214.851 us; speedup 1.0000x reference)
//
#include <hip/hip_runtime.h>

#define BN 8192
#define EE 262144
#define HIDD 128
#define NRBF 64
#define NBLK 4
#define TLUT 2048
#define CAP 128
#define MR 16
#define FR 8
#define RCUTF 6.0f
#define GAMMAF (10.0f / 36.0f)

typedef unsigned short u16;
typedef __attribute__((ext_vector_type(8))) short short8x;
typedef __attribute__((ext_vector_type(8))) unsigned short u16x8;
typedef __attribute__((ext_vector_type(4))) float f32x4;

__device__ __forceinline__ float silu_f(float v) {
    return v / (1.0f + __expf(-v));
}
__device__ __forceinline__ float bf2f(u16 u) {
    return __uint_as_float(((unsigned)u) << 16);
}
__device__ __forceinline__ u16 f2bf(float f) {
    unsigned u = __float_as_uint(f);
    unsigned r = u + 0x7FFFu + ((u >> 16) & 1u);
    return (u16)(r >> 16);
}

// ---- k_pe: weight transposes + edge bucketing (all LDS-free) ----------------
__global__ void k_pe(const int* __restrict__ ei, const float* __restrict__ pos,
                     const float* __restrict__ liw, const float* __restrict__ nw1,
                     const float* __restrict__ nw2, const float* __restrict__ ro1,
                     int* __restrict__ cnt, int* __restrict__ meta,
                     u16* __restrict__ liwT, u16* __restrict__ nw1T,
                     u16* __restrict__ nw2T, u16* __restrict__ ro1T,
                     float* __restrict__ out, int out_n) {
    int tid = threadIdx.x, blk = blockIdx.x;
    if (blk < 1024) {
        int e = blk * 256 + tid;
        int s = ei[e];
        int d = ei[EE + e];
        float dx = pos[s * 3 + 0] - pos[d * 3 + 0];
        float dy = pos[s * 3 + 1] - pos[d * 3 + 1];
        float dz = pos[s * 3 + 2] - pos[d * 3 + 2];
        float dist = fminf(sqrtf(dx * dx + dy * dy + dz * dz), RCUTF);
        int i0 = (int)(dist * ((TLUT - 1) / RCUTF) + 0.5f);
        i0 = i0 > TLUT - 1 ? TLUT - 1 : i0;
        int p = atomicAdd(&cnt[d], 1);
        if (p < CAP) meta[(size_t)d * CAP + p] = (i0 << 13) | s;
    } else if (blk < 1792) {
        int id = (blk - 1024) * 256 + tid;     // [0, 196608) = 12*16384
        int which = id >> 14;
        int r = id & 16383;
        int n = r >> 7, k = r & 127;
        const float* src = which < 4 ? liw : (which < 8 ? nw1 : nw2);
        u16* dst = which < 4 ? liwT : (which < 8 ? nw1T : nw2T);
        int b = which & 3;
        dst[b * 16384 + n * 128 + k] = f2bf(src[(size_t)b * 16384 + k * 128 + n]);
    } else {
        int id = (blk - 1792) * 256 + tid;     // [0, 8192)
        int n = id >> 7, k = id & 127;
        ro1T[n * 128 + k] = f2bf(ro1[(size_t)k * 64 + n]);
        if (blk == 1792 && tid < out_n) out[tid] = 0.0f;
    }
}

// ---- k_le: filter-LUT MLP (blocks 0..255) | embed + x0 (blocks 256..767) ----
__global__ __launch_bounds__(256, 2) void k_le(
    const float* __restrict__ W1a, const float* __restrict__ b1a,
    const float* __restrict__ W2a, const float* __restrict__ b2a,
    u16* __restrict__ lutall,
    const int* __restrict__ Z, const float* __restrict__ ew,
    const u16* __restrict__ liwT0, float* __restrict__ h,
    u16* __restrict__ xb) {
    __shared__ union {
        struct { float As[32 * 33]; float Ws[32 * 128]; float T2[32 * 128]; } lu;
        struct { u16 Wt[128][136]; u16 Ab[MR][136]; } ex;
    } S;
    int tid = threadIdx.x, blk = blockIdx.x;
    if (blk < 256) {
        int net = blk >> 6;
        int r0l = (blk & 63) * 32;
        const float* W1 = W1a + (size_t)net * NRBF * HIDD;
        const float* b1 = b1a + net * HIDD;
        const float* W2 = W2a + (size_t)net * HIDD * HIDD;
        const float* b2 = b2a + net * HIDD;
        u16* lutp = lutall + (size_t)net * TLUT * HIDD;
        int tx = tid & 31, ty = tid >> 5;
        int c0 = tx * 4, rr = ty * 4;
        float acc[4][4] = {};
        for (int kc = 0; kc < NRBF; kc += 32) {
            int lr = tid >> 3, lc = (tid & 7) * 4;
            float dt = (r0l + lr) * (RCUTF / (TLUT - 1));
#pragma unroll
            for (int j = 0; j < 4; ++j) {
                float c = (kc + lc + j) * (RCUTF / 63.0f);
                float u = dt - c;
                S.lu.As[lr * 33 + lc + j] = __expf(-GAMMAF * u * u);
            }
#pragma unroll
            for (int j = 0; j < 4; ++j) {
                int idx = tid + j * 256;
                int wr = idx >> 5, wc = (idx & 31) * 4;
                *(float4*)&S.lu.Ws[wr * 128 + wc] =
                    *(const float4*)&W1[(size_t)(kc + wr) * HIDD + wc];
            }
            __syncthreads();
#pragma unroll 8
            for (int k = 0; k < 32; ++k) {
                float4 wv = *(float4*)&S.lu.Ws[k * 128 + c0];
                float a0 = S.lu.As[(rr + 0) * 33 + k];
                float a1 = S.lu.As[(rr + 1) * 33 + k];
                float a2 = S.lu.As[(rr + 2) * 33 + k];
                float a3 = S.lu.As[(rr + 3) * 33 + k];
                acc[0][0] += a0 * wv.x; acc[0][1] += a0 * wv.y; acc[0][2] += a0 * wv.z; acc[0][3] += a0 * wv.w;
                acc[1][0] += a1 * wv.x; acc[1][1] += a1 * wv.y; acc[1][2] += a1 * wv.z; acc[1][3] += a1 * wv.w;
                acc[2][0] += a2 * wv.x; acc[2][1] += a2 * wv.y; acc[2][2] += a2 * wv.z; acc[2][3] += a2 * wv.w;
                acc[3][0] += a3 * wv.x; acc[3][1] += a3 * wv.y; acc[3][2] += a3 * wv.z; acc[3][3] += a3 * wv.w;
            }
            __syncthreads();
        }
#pragma unroll
        for (int i = 0; i < 4; ++i)
#pragma unroll
            for (int j = 0; j < 4; ++j)
                S.lu.T2[(rr + i) * 128 + c0 + j] = silu_f(acc[i][j] + b1[c0 + j]);
        float acc2[4][4] = {};
        __syncthreads();
        for (int kc = 0; kc < HIDD; kc += 32) {
#pragma unroll
            for (int j = 0; j < 4; ++j) {
                int idx = tid + j * 256;
                int wr = idx >> 5, wc = (idx & 31) * 4;
                *(float4*)&S.lu.Ws[wr * 128 + wc] =
                    *(const float4*)&W2[(size_t)(kc + wr) * HIDD + wc];
            }
            __syncthreads();
#pragma unroll 8
            for (int k = 0; k < 32; ++k) {
                float4 wv = *(float4*)&S.lu.Ws[k * 128 + c0];
                float a0 = S.lu.T2[(rr + 0) * 128 + kc + k];
                float a1 = S.lu.T2[(rr + 1) * 128 + kc + k];
                float a2 = S.lu.T2[(rr + 2) * 128 + kc + k];
                float a3 = S.lu.T2[(rr + 3) * 128 + kc + k];
                acc2[0][0] += a0 * wv.x; acc2[0][1] += a0 * wv.y; acc2[0][2] += a0 * wv.z; acc2[0][3] += a0 * wv.w;
                acc2[1][0] += a1 * wv.x; acc2[1][1] += a1 * wv.y; acc2[1][2] += a1 * wv.z; acc2[1][3] += a1 * wv.w;
                acc2[2][0] += a2 * wv.x; acc2[2][1] += a2 * wv.y; acc2[2][2] += a2 * wv.z; acc2[2][3] += a2 * wv.w;
                acc2[3][0] += a3 * wv.x; acc2[3][1] += a3 * wv.y; acc2[3][2] += a3 * wv.z; acc2[3][3] += a3 * wv.w;
            }
            __syncthreads();
        }
#pragma unroll
        for (int i = 0; i < 4; ++i) {
            int t = r0l + rr + i;
            ushort4 o;
            o.x = f2bf(acc2[i][0] + b2[c0 + 0]);
            o.y = f2bf(acc2[i][1] + b2[c0 + 1]);
            o.z = f2bf(acc2[i][2] + b2[c0 + 2]);
            o.w = f2bf(acc2[i][3] + b2[c0 + 3]);
            *(ushort4*)&lutp[(size_t)t * HIDD + c0] = o;
        }
    } else {
        int r0 = (blk - 256) * MR;
        {
            int row = tid >> 4, c8 = (tid & 15) * 8;
            int z = Z[r0 + row];
            const float* er = ew + (size_t)z * HIDD + c8;
            float* hr = h + (size_t)(r0 + row) * HIDD + c8;
            float4 v0 = *(const float4*)er;
            float4 v1 = *(const float4*)(er + 4);
            *(float4*)hr = v0;
            *(float4*)(hr + 4) = v1;
            ushort4 a0, a1;
            a0.x = f2bf(v0.x); a0.y = f2bf(v0.y); a0.z = f2bf(v0.z); a0.w = f2bf(v0.w);
            a1.x = f2bf(v1.x); a1.y = f2bf(v1.y); a1.z = f2bf(v1.z); a1.w = f2bf(v1.w);
            *(ushort4*)&S.ex.Ab[row][c8] = a0;
            *(ushort4*)&S.ex.Ab[row][c8 + 4] = a1;
        }
        for (int idx = tid; idx < 2048; idx += 256) {
            int r = idx >> 4, c = (idx & 15) * 8;
            *(float4*)&S.ex.Wt[r][c] = *(const float4*)&liwT0[r * HIDD + c];
        }
        __syncthreads();
        int w = tid >> 6, l = tid & 63;
        int m = l & 15, q4 = l >> 4, q8 = q4 * 8;
        f32x4 a0 = {0, 0, 0, 0}, a1 = {0, 0, 0, 0};
#pragma unroll
        for (int kc = 0; kc < 128; kc += 32) {
            short8x av = *(const short8x*)&S.ex.Ab[m][kc + q8];
            short8x b0 = *(const short8x*)&S.ex.Wt[w * 32 + m][kc + q8];
            short8x b1 = *(const short8x*)&S.ex.Wt[w * 32 + 16 + m][kc + q8];
            a0 = __builtin_amdgcn_mfma_f32_16x16x32_bf16(av, b0, a0, 0, 0, 0);
            a1 = __builtin_amdgcn_mfma_f32_16x16x32_bf16(av, b1, a1, 0, 0, 0);
        }
        int c = w * 32 + m;
#pragma unroll
        for (int r = 0; r < 4; ++r) {
            int row = q4 * 4 + r;
            u16* xr = xb + (size_t)(r0 + row) * HIDD;
            xr[c] = f2bf(a0[r]);
            xr[c + 16] = f2bf(a1[r]);
        }
    }
}

// ---- fused gather + node MLP + LN + (next-x | readout) ----------------------
// 512 thr (8 waves), FR=8 rows/block, 1024 blocks. Wave w owns dst r0+w.
// doSort=1 (iter 0): bitonic-sort the bucket (canonical order) + write back,
// making all 4 iterations' accumulation order deterministic across replays.
__global__ __launch_bounds__(512, 4) void k_fiter(
    const int* __restrict__ cnt, int* __restrict__ meta,
    const u16* __restrict__ lut, const u16* __restrict__ xin,
    float* __restrict__ h,
    const u16* __restrict__ w1t, const float* __restrict__ b1,
    const u16* __restrict__ w2t, const float* __restrict__ b2,
    const float* __restrict__ g, const float* __restrict__ bb,
    const u16* __restrict__ w3t, u16* __restrict__ xout, int last, int doSort,
    const float* __restrict__ rb1, const float* __restrict__ rw2,
    const float* __restrict__ rb2, float* __restrict__ out) {
    __shared__ u16 SH[2176 + 128 * 136];     // Ab(8x136) | Tb(8x136) | Wt(128x136)
    __shared__ float RED[152];               // S[64] Q[64] MU[8] RS[8] ROUT[8]
    int tid = threadIdx.x;
    int w = tid >> 6, l = tid & 63;
    int m = l & 15, q4 = l >> 4, q8 = q4 * 8;
    int r0 = blockIdx.x * FR;
    u16* Ab = SH;
    u16* Tb = SH + 1088;
    u16* Wt = SH + 2176;

    // --- gather: wave w owns dst r0+w; lane = (quarter q4, feat-group m) -----
    {
        int dst = r0 + w;
        int n = cnt[dst];
        n = n > CAP ? CAP : n;
        int* mp = meta + (size_t)dst * CAP;
        int mA = l < n ? mp[l] : 0x7FFFFFFF;
        int mB = 64 + l < n ? mp[64 + l] : 0x7FFFFFFF;
        if (doSort) {
            // ascending bitonic sort of 128 values (virtual idx: mA->l, mB->l+64)
#pragma unroll
            for (int k = 2; k <= 128; k <<= 1) {
#pragma unroll
                for (int j = k >> 1; j > 0; j >>= 1) {
                    if (j == 64) {
                        int lo = mA < mB ? mA : mB;
                        int hi = mA < mB ? mB : mA;
                        mA = lo;
                        mB = hi;
                    } else {
                        int up_a = ((l & k) == 0) ? 1 : 0;
                        int up_b = (((l + 64) & k) == 0) ? 1 : 0;
                        int keep_low = ((l & j) == 0) ? 1 : 0;
                        int pa = __shfl_xor(mA, j);
                        int pb = __shfl_xor(mB, j);
                        int amin = mA < pa ? mA : pa, amax = mA < pa ? pa : mA;
                        int bmin = mB < pb ? mB : pb, bmax = mB < pb ? pb : mB;
                        mA = (keep_low == up_a) ? amin : amax;
                        mB = (keep_low == up_b) ? bmin : bmax;
                    }
                }
            }
            mp[l] = mA;
            mp[64 + l] = mB;
        }
        float ax[8] = {};
        int tmax = (n + 3) >> 2;
#pragma unroll 2
        for (int t = 0; t < tmax; ++t) {
            int e4 = t * 4 + q4;
            int md = __shfl(e4 < 64 ? mA : mB, e4 & 63);
            if (e4 < n) {
                int s = md & 8191;
                int i0 = md >> 13;
                u16x8 lv = *(const u16x8*)&lut[((size_t)i0 << 7) + 8 * m];
                u16x8 xv = *(const u16x8*)&xin[((size_t)s << 7) + 8 * m];
#pragma unroll
                for (int j = 0; j < 8; ++j)
                    ax[j] = fmaf(bf2f(lv[j]), bf2f(xv[j]), ax[j]);
            }
        }
#pragma unroll
        for (int j = 0; j < 8; ++j) {
            ax[j] += __shfl_xor(ax[j], 16);
            ax[j] += __shfl_xor(ax[j], 32);
        }
        if (q4 == 0) {
            u16x8 o;
#pragma unroll
            for (int j = 0; j < 8; ++j) o[j] = f2bf(ax[j]);
            *(u16x8*)&Ab[w * 136 + 8 * m] = o;
        }
    }
    for (int idx = tid; idx < 2048; idx += 512) {
        int r = idx >> 4, c = (idx & 15) * 8;
        *(float4*)&Wt[r * 136 + c] = *(const float4*)&w1t[r * HIDD + c];
    }
    __syncthreads();

    // --- GEMM1: wave w -> cols w*16..+15 (rows 0..7 real) --------------------
    int col = w * 16 + m;
    f32x4 ac1 = {0, 0, 0, 0};
#pragma unroll
    for (int kc = 0; kc < 128; kc += 32) {
        short8x av = *(const short8x*)&Ab[m * 136 + kc + q8];
        short8x bv = *(const short8x*)&Wt[(w * 16 + m) * 136 + kc + q8];
        ac1 = __builtin_amdgcn_mfma_f32_16x16x32_bf16(av, bv, ac1, 0, 0, 0);
    }
    __syncthreads();
    {
        float bv = b1[col];
        if (q4 < 2) {
#pragma unroll
            for (int r = 0; r < 4; ++r)
                Tb[(q4 * 4 + r) * 136 + col] = f2bf(silu_f(ac1[r] + bv));
        }
    }
    for (int idx = tid; idx < 2048; idx += 512) {
        int r = idx >> 4, c = (idx & 15) * 8;
        *(float4*)&Wt[r * 136 + c] = *(const float4*)&w2t[r * HIDD + c];
    }
    __syncthreads();

    // --- GEMM2 + bias + residual ---------------------------------------------
    f32x4 ac2 = {0, 0, 0, 0};
#pragma unroll
    for (int kc = 0; kc < 128; kc += 32) {
        short8x av = *(const short8x*)&Tb[m * 136 + kc + q8];
        short8x bv = *(const short8x*)&Wt[(w * 16 + m) * 136 + kc + q8];
        ac2 = __builtin_amdgcn_mfma_f32_16x16x32_bf16(av, bv, ac2, 0, 0, 0);
    }
    float v[4];
    if (q4 < 2) {
        float bv = b2[col];
#pragma unroll
        for (int r = 0; r < 4; ++r) {
            int row = q4 * 4 + r;
            v[r] = ac2[r] + bv + h[(size_t)(r0 + row) * HIDD + col];
        }
    }
    __syncthreads();

    // --- LN partials + stage W3 ----------------------------------------------
    if (q4 < 2) {
#pragma unroll
        for (int r = 0; r < 4; ++r) {
            float s = v[r], q = v[r] * v[r];
#pragma unroll
            for (int mm = 1; mm < 16; mm <<= 1) {
                s += __shfl_xor(s, mm);
                q += __shfl_xor(q, mm);
            }
            if (m == 0) {
                RED[w * 8 + q4 * 4 + r] = s;
                RED[64 + w * 8 + q4 * 4 + r] = q;
            }
        }
    }
    {
        int rows3 = last ? 64 : 128;
        for (int idx = tid; idx < rows3 * 16; idx += 512) {
            int r = idx >> 4, c = (idx & 15) * 8;
            *(float4*)&Wt[r * 136 + c] = *(const float4*)&w3t[r * HIDD + c];
        }
    }
    __syncthreads();
    if (tid < 8) {
        float s = 0.0f, q = 0.0f;
#pragma unroll
        for (int ww = 0; ww < 8; ++ww) {
            s += RED[ww * 8 + tid];
            q += RED[64 + ww * 8 + tid];
        }
        float mu = s * (1.0f / 128.0f);
        float var = q * (1.0f / 128.0f) - mu * mu;
        RED[128 + tid] = mu;
        RED[136 + tid] = rsqrtf(var + 1e-5f);
    }
    __syncthreads();
    if (q4 < 2) {
        float gv = g[col], bbv = bb[col];
#pragma unroll
        for (int r = 0; r < 4; ++r) {
            int row = q4 * 4 + r;
            float mu = RED[128 + row], rs = RED[136 + row];
            float o = (v[r] - mu) * rs * gv + bbv;
            if (!last) h[(size_t)(r0 + row) * HIDD + col] = o;
            Ab[row * 136 + col] = f2bf(last ? silu_f(o) : o);
        }
    }
    __syncthreads();

    // --- GEMM3: next x  OR  readout ------------------------------------------
    if (!last) {
        f32x4 ac3 = {0, 0, 0, 0};
#pragma unroll
        for (int kc = 0; kc < 128; kc += 32) {
            short8x av = *(const short8x*)&Ab[m * 136 + kc + q8];
            short8x bv = *(const short8x*)&Wt[(w * 16 + m) * 136 + kc + q8];
            ac3 = __builtin_amdgcn_mfma_f32_16x16x32_bf16(av, bv, ac3, 0, 0, 0);
        }
        if (q4 < 2) {
#pragma unroll
            for (int r = 0; r < 4; ++r) {
                int row = q4 * 4 + r;
                xout[(size_t)(r0 + row) * HIDD + col] = f2bf(ac3[r]);
            }
        }
    } else {
        float tsum = 0.0f;
        if (w < 4) {
            f32x4 ac3 = {0, 0, 0, 0};
#pragma unroll
            for (int kc = 0; kc < 128; kc += 32) {
                short8x av = *(const short8x*)&Ab[m * 136 + kc + q8];
                short8x bv = *(const short8x*)&Wt[(w * 16 + m) * 136 + kc + q8];
                ac3 = __builtin_amdgcn_mfma_f32_16x16x32_bf16(av, bv, ac3, 0, 0, 0);
            }
            if (q4 < 2) {
                float bv = rb1[col], wv = rw2[col];
#pragma unroll
                for (int r = 0; r < 4; ++r) tsum += silu_f(ac3[r] + bv) * wv;
            }
#pragma unroll
            for (int mm = 1; mm < 64; mm <<= 1) tsum += __shfl_xor(tsum, mm);
            if (l == 0) RED[144 + w] = tsum;
        }
        __syncthreads();
        if (tid == 0) {
            float tot = RED[144] + RED[145] + RED[146] + RED[147] +
                        (float)FR * rb2[0];
            atomicAdd(&out[blockIdx.x >> 4], tot);
        }
    }
}

extern "C" void kernel_launch(void* const* d_in, const int* in_sizes, int n_in,
                              void* d_out, int out_size, void* d_ws, size_t ws_size,
                              hipStream_t stream) {
    const int*   Z   = (const int*)d_in[0];
    const float* pos = (const float*)d_in[1];
    const int*   ei  = (const int*)d_in[2];
    const float* ew  = (const float*)d_in[3];
    const float* ew1 = (const float*)d_in[4];
    const float* eb1 = (const float*)d_in[5];
    const float* ew2 = (const float*)d_in[6];
    const float* eb2 = (const float*)d_in[7];
    const float* liw = (const float*)d_in[8];
    const float* nw1 = (const float*)d_in[9];
    const float* nb1 = (const float*)d_in[10];
    const float* nw2 = (const float*)d_in[11];
    const float* nb2 = (const float*)d_in[12];
    const float* lng = (const float*)d_in[13];
    const float* lnb = (const float*)d_in[14];
    const float* rw1 = (const float*)d_in[15];
    const float* rb1 = (const float*)d_in[16];
    const float* rw2 = (const float*)d_in[17];
    const float* rb2 = (const float*)d_in[18];
    float* out = (float*)d_out;

    float* h      = (float*)d_ws;                            // 4 MB
    u16*   xb0    = (u16*)(h + (size_t)BN * HIDD);           // 2 MB
    u16*   xb1    = xb0 + (size_t)BN * HIDD;                 // 2 MB
    u16*   lutall = xb1 + (size_t)BN * HIDD;                 // 2 MB
    u16*   liwT   = lutall + (size_t)NBLK * TLUT * HIDD;     // 128 KB
    u16*   nw1T   = liwT + (size_t)NBLK * HIDD * HIDD;
    u16*   nw2T   = nw1T + (size_t)NBLK * HIDD * HIDD;
    u16*   ro1T   = nw2T + (size_t)NBLK * HIDD * HIDD;       // 16 KB
    int*   cnt    = (int*)(ro1T + 64 * HIDD);                // 32 KB
    int*   meta   = (int*)(cnt + BN);                        // 4 MB

    (void)hipMemsetAsync(cnt, 0, BN * sizeof(int), stream);
    k_pe<<<1824, 256, 0, stream>>>(ei, pos, liw, nw1, nw2, rw1,
                                   cnt, meta, liwT, nw1T, nw2T, ro1T,
                                   out, out_size);
    k_le<<<768, 256, 0, stream>>>(ew1, eb1, ew2, eb2, lutall,
                                  Z, ew, liwT, h, xb0);

    u16* xbuf[2] = {xb0, xb1};
    for (int i = 0; i < NBLK; ++i) {
        int last = (i == NBLK - 1);
        k_fiter<<<BN / FR, 512, 0, stream>>>(
            cnt, meta, lutall + (size_t)i * TLUT * HIDD, xbuf[i & 1], h,
            nw1T + (size_t)i * HIDD * HIDD, nb1 + i * HIDD,
            nw2T + (size_t)i * HIDD * HIDD, nb2 + i * HIDD,
            lng + i * HIDD, lnb + i * HIDD,
            last ? ro1T : liwT + (size_t)(i + 1) * HIDD * HIDD,
            last ? (u16*)nullptr : xbuf[(i + 1) & 1],
            last, (i == 0) ? 1 : 0, rb1, rw2, rb2, out);
    }
}